// Round 15
// baseline (184.141 us; speedup 1.0000x reference)
//
#include <hip/hip_runtime.h>
#include <stdint.h>

// QuantizedLinear: out[N,OUT_F] = requant(int8gemm(x, W^T) + bias)
// x: [8192,4096] int8 (pushed int32), W: [4096,4096] int8 (pushed int32)
// out: int8 values stored as int32 (harness reads d_out as np.int32)
//
// r15: arithmetic-intensity attack. i8's 2x matrix rate makes LDS READ VOLUME
// the binding term (additive model matched r7-r14 exactly). 4 waves, each
// owning a 128x128 output tile (acc 256 VGPR, 1 wave/SIMD by design,
// launch_bounds(256,1) -> 512-reg budget, no spill at ~415): A and B
// fragment duplication both drop to 2x -> 64 KB reads/tile/CU (was 96).
// r12-proven counted-wait schedule: STAGE8 -> vmcnt(8) -> barrier ->
// READ16 (inline asm) -> lgkmcnt(15) -> 32 MFMA on prev tile's regs.
// 32-row fragment-ordered panels (r6-verified), 4-slot ring, XCD swizzle.

#define M_DIM 8192
#define N_DIM 4096
#define K_DIM 4096
#define BM 256
#define BN 256
#define NKT2 (K_DIM / 32)            // 128 k-subtiles in panel layout
#define NBLK ((M_DIM / BM) * (N_DIM / BN))   // 512
#define SLOT 16384                   // 16 KiB per slot (A or B half)

using i32x4  = __attribute__((ext_vector_type(4))) int;
using i32x16 = __attribute__((ext_vector_type(16))) int;

typedef const __attribute__((address_space(1))) uint32_t* gptr_t;
typedef __attribute__((address_space(3))) uint32_t* lptr_t;

__device__ __forceinline__ void gload_lds16(const void* g, void* l) {
    __builtin_amdgcn_global_load_lds((gptr_t)g, (lptr_t)l, 16, 0, 0);
}

__device__ __forceinline__ int pack4(i32x4 v) {
    return (int)(((unsigned)v.x & 0xFFu) | (((unsigned)v.y & 0xFFu) << 8) |
                 (((unsigned)v.z & 0xFFu) << 16) | (((unsigned)v.w) << 24));
}

// int32 [rows][K_DIM] -> fragment-ordered panels [rows/32][NKT2][1024]
// block (rb,kt): byte[l*16+j] = (int8)src[rb*32 + (l&31)][kt*32 + (l>>5)*16 + j]
__global__ void pack_panels32_kernel(const int* __restrict__ src, int8_t* __restrict__ dst,
                                     int n_blocks) {
    int gid = blockIdx.x * blockDim.x + threadIdx.x;
    int blk = gid >> 6;
    int l = gid & 63;
    if (blk >= n_blocks) return;
    int rb = blk >> 7;               // / NKT2
    int kt = blk & (NKT2 - 1);
    const i32x4* s4 = (const i32x4*)(src + (size_t)(rb * 32 + (l & 31)) * K_DIM
                                         + kt * 32 + (l >> 5) * 16);
    i32x4 o;
    o.x = pack4(s4[0]); o.y = pack4(s4[1]); o.z = pack4(s4[2]); o.w = pack4(s4[3]);
    *(i32x4*)(dst + (size_t)blk * 1024 + l * 16) = o;
}

#define MFMA32(a, b, c) __builtin_amdgcn_mfma_i32_32x32x32_i8((a), (b), (c), 0, 0, 0)

// Inline-asm LDS read: compiler inserts NO automatic lgkm waits.
#define DSR(dst, base, off) \
    asm volatile("ds_read_b128 %0, %1 offset:%2" : "=&v"(dst) : "v"(base), "i"(off))

// 16 prefetch reads: A rsubs 0..3 (own quarter) x ksubs 0..1, B csubs same.
// Bases already include wave offset + lane*16 + slot base. Offsets <= 7168.
#define READ16(NS, AB, BB)                                              \
    DSR(fA[NS][0][0], AB, 0);    DSR(fA[NS][0][1], AB, 2048);           \
    DSR(fA[NS][0][2], AB, 4096); DSR(fA[NS][0][3], AB, 6144);           \
    DSR(fA[NS][1][0], AB, 1024); DSR(fA[NS][1][1], AB, 3072);           \
    DSR(fA[NS][1][2], AB, 5120); DSR(fA[NS][1][3], AB, 7168);           \
    DSR(fB[NS][0][0], BB, 0);    DSR(fB[NS][0][1], BB, 2048);           \
    DSR(fB[NS][0][2], BB, 4096); DSR(fB[NS][0][3], BB, 6144);           \
    DSR(fB[NS][1][0], BB, 1024); DSR(fB[NS][1][1], BB, 3072);           \
    DSR(fB[NS][1][2], BB, 5120); DSR(fB[NS][1][3], BB, 7168);

// 16 independent MFMAs on set CS, k-half K (4 rsubs x 4 csubs).
#define MFMA_K(CS, K)                                                   \
    acc[0][0] = MFMA32(fA[CS][K][0], fB[CS][K][0], acc[0][0]);          \
    acc[0][1] = MFMA32(fA[CS][K][0], fB[CS][K][1], acc[0][1]);          \
    acc[0][2] = MFMA32(fA[CS][K][0], fB[CS][K][2], acc[0][2]);          \
    acc[0][3] = MFMA32(fA[CS][K][0], fB[CS][K][3], acc[0][3]);          \
    acc[1][0] = MFMA32(fA[CS][K][1], fB[CS][K][0], acc[1][0]);          \
    acc[1][1] = MFMA32(fA[CS][K][1], fB[CS][K][1], acc[1][1]);          \
    acc[1][2] = MFMA32(fA[CS][K][1], fB[CS][K][2], acc[1][2]);          \
    acc[1][3] = MFMA32(fA[CS][K][1], fB[CS][K][3], acc[1][3]);          \
    acc[2][0] = MFMA32(fA[CS][K][2], fB[CS][K][0], acc[2][0]);          \
    acc[2][1] = MFMA32(fA[CS][K][2], fB[CS][K][1], acc[2][1]);          \
    acc[2][2] = MFMA32(fA[CS][K][2], fB[CS][K][2], acc[2][2]);          \
    acc[2][3] = MFMA32(fA[CS][K][2], fB[CS][K][3], acc[2][3]);          \
    acc[3][0] = MFMA32(fA[CS][K][3], fB[CS][K][0], acc[3][0]);          \
    acc[3][1] = MFMA32(fA[CS][K][3], fB[CS][K][1], acc[3][1]);          \
    acc[3][2] = MFMA32(fA[CS][K][3], fB[CS][K][2], acc[3][2]);          \
    acc[3][3] = MFMA32(fA[CS][K][3], fB[CS][K][3], acc[3][3]);

// Stage one tile into slot S: wave stages A rsubs {2w,2w+1} x 2 ksubs and
// B csubs {2w,2w+1} x 2 ksubs = 8 x 1KB gload_lds. Pointers advance 2048/tile.
#define STAGE8(S)                                                               \
    gload_lds16(AgS,         ldsA + (S) * SLOT + (2 * wave) * 2048);            \
    gload_lds16(AgS  + 1024, ldsA + (S) * SLOT + (2 * wave) * 2048 + 1024);     \
    gload_lds16(AgS2,        ldsA + (S) * SLOT + (2 * wave + 1) * 2048);        \
    gload_lds16(AgS2 + 1024, ldsA + (S) * SLOT + (2 * wave + 1) * 2048 + 1024); \
    gload_lds16(BgS,         ldsB + (S) * SLOT + (2 * wave) * 2048);            \
    gload_lds16(BgS  + 1024, ldsB + (S) * SLOT + (2 * wave) * 2048 + 1024);     \
    gload_lds16(BgS2,        ldsB + (S) * SLOT + (2 * wave + 1) * 2048);        \
    gload_lds16(BgS2 + 1024, ldsB + (S) * SLOT + (2 * wave + 1) * 2048 + 1024); \
    AgS += 2048; AgS2 += 2048; BgS += 2048; BgS2 += 2048;

// Steady tile t: stage t+2, land t+1 (vmcnt(8): leaves t+2's 8 in flight),
// asm-read t+1, wait prev tile's 16 reads (lgkmcnt(15), in-order retire),
// 32 MFMA on tile t's registers.
#define TILE_FULL(SS, AB, BB, NS, CS)                                   \
  { STAGE8(SS)                                                          \
    asm volatile("s_waitcnt vmcnt(8)" ::: "memory");                    \
    __builtin_amdgcn_s_barrier();                                       \
    READ16(NS, AB, BB)                                                  \
    asm volatile("s_waitcnt lgkmcnt(15)" ::: "memory");                 \
    __builtin_amdgcn_sched_barrier(0);                                  \
    __builtin_amdgcn_s_setprio(1);                                      \
    MFMA_K(CS, 0)                                                       \
    MFMA_K(CS, 1)                                                       \
    __builtin_amdgcn_s_setprio(0); }

__global__ __launch_bounds__(256, 1)
void qgemm32_kernel(const int8_t* __restrict__ xp, const int8_t* __restrict__ wp,
                    const int* __restrict__ bias, const float* __restrict__ wscale,
                    const float* __restrict__ iscale, const float* __restrict__ oscale,
                    const int* __restrict__ zp, int* __restrict__ out) {
    extern __shared__ int8_t lds[];
    int8_t* ldsA = lds;               // 4 slots * 16 KiB, [rsub 0..7][ksub 0..1][1024]
    int8_t* ldsB = lds + 4 * SLOT;    // 4 slots * 16 KiB, [csub 0..7][ksub 0..1][1024]

    const int tid  = threadIdx.x;
    const int wave = tid >> 6;        // 0..3
    const int lane = tid & 63;

    // XCD-bijective swizzle (NBLK = 512, divisible by 8)
    int b = blockIdx.x;
    int s = (b & 7) * (NBLK >> 3) + (b >> 3);
    const int bcol = (s & 15) * BN;   // N_DIM/BN = 16
    const int brow = (s >> 4) * BM;

    const int wr = wave >> 1;         // 0..1  (M half: rsubs wr*4..wr*4+3)
    const int wc = wave & 1;          // 0..1  (N half: csubs wc*4..wc*4+3)

    // staging sources (fragment-ordered panels; advance 2048 B per K-tile)
    const int rb0 = brow >> 5;        // 8 rsubs per tile
    const int cb0 = bcol >> 5;
    const int8_t* AgS  = xp + ((size_t)(rb0 + 2 * wave)     * NKT2) * 1024 + lane * 16;
    const int8_t* AgS2 = xp + ((size_t)(rb0 + 2 * wave + 1) * NKT2) * 1024 + lane * 16;
    const int8_t* BgS  = wp + ((size_t)(cb0 + 2 * wave)     * NKT2) * 1024 + lane * 16;
    const int8_t* BgS2 = wp + ((size_t)(cb0 + 2 * wave + 1) * NKT2) * 1024 + lane * 16;

    // asm ds_read bases per slot (include wave quarter + lane*16)
    const unsigned aA0 = (unsigned)(uintptr_t)(ldsA + wr * 8192 + lane * 16);
    const unsigned aA1 = aA0 + SLOT, aA2 = aA0 + 2 * SLOT, aA3 = aA0 + 3 * SLOT;
    const unsigned aB0 = (unsigned)(uintptr_t)(ldsB + wc * 8192 + lane * 16);
    const unsigned aB1 = aB0 + SLOT, aB2 = aB0 + 2 * SLOT, aB3 = aB0 + 3 * SLOT;

    i32x16 acc[4][4] = {};            // 256 VGPR accumulator (128x128 per wave)
    i32x4 fA[2][2][4];                // [set][ksub][rsub] — static indices only
    i32x4 fB[2][2][4];                // [set][ksub][csub]

    // ---- prologue: stage tile0->slot0, tile1->slot1; land tile0; read set0 ----
    STAGE8(0)
    STAGE8(1)
    asm volatile("s_waitcnt vmcnt(8)" ::: "memory");   // tile0's 8 landed
    __builtin_amdgcn_s_barrier();
    READ16(0, aA0, aB0)

    // ---- main loop: t = 0..59 in 15 groups of 4 ----
    // tile t: stage slot (t+2)%4, read slot (t+1)%4 into set (t+1)%2, MFMA set t%2
    for (int i = 0; i < 15; ++i) {
        TILE_FULL(2, aA1, aB1, 1, 0)  // t%4==0
        TILE_FULL(3, aA2, aB2, 0, 1)  // t%4==1
        TILE_FULL(0, aA3, aB3, 1, 0)  // t%4==2
        TILE_FULL(1, aA0, aB0, 0, 1)  // t%4==3
    }
    // ---- t=60 (stage tile62->slot2), t=61 (stage tile63->slot3) ----
    TILE_FULL(2, aA1, aB1, 1, 0)
    TILE_FULL(3, aA2, aB2, 0, 1)
    // ---- t=62: no stage; drain staging; read slot3 into set1; MFMA set0 ----
    {
        asm volatile("s_waitcnt vmcnt(0)" ::: "memory");
        __builtin_amdgcn_s_barrier();
        READ16(1, aA3, aB3)
        asm volatile("s_waitcnt lgkmcnt(15)" ::: "memory");
        __builtin_amdgcn_sched_barrier(0);
        __builtin_amdgcn_s_setprio(1);
        MFMA_K(0, 0)
        MFMA_K(0, 1)
        __builtin_amdgcn_s_setprio(0);
    }
    // ---- t=63: final MFMA (set1); wait its reads ----
    asm volatile("s_waitcnt lgkmcnt(0)" ::: "memory");
    __builtin_amdgcn_sched_barrier(0);
    MFMA_K(1, 0)
    MFMA_K(1, 1)

    // ---- epilogue: out = clip(round((acc + bias) * (is*ws/os) + zp)) as int32 ----
    // 32x32 C/D layout (HW-verified): col = lane&31, row = (reg&3) + 8*(reg>>2) + 4*(lane>>5)
    const float is_v = iscale[0];
    const float os_v = oscale[0];
    const float zpf = (float)zp[0];
    #pragma unroll
    for (int c = 0; c < 4; c++) {
        int col = bcol + wc * 128 + c * 32 + (lane & 31);
        float sf = (is_v * wscale[col]) / os_v;
        int bz = bias[col];
        #pragma unroll
        for (int r = 0; r < 4; r++) {
            int rowb = brow + wr * 128 + r * 32 + 4 * (lane >> 5);
            #pragma unroll
            for (int reg = 0; reg < 16; reg++) {
                int row = rowb + (reg & 3) + 8 * (reg >> 2);
                float v = (float)(acc[r][c][reg] + bz) * sf + zpf;
                v = rintf(v);
                v = fminf(fmaxf(v, -128.0f), 127.0f);
                out[(size_t)row * N_DIM + col] = (int)v;
            }
        }
    }
}

#define MFMA_I8(a, b, c) __builtin_amdgcn_mfma_i32_16x16x64_i8((a), (b), (c), 0, 0, 0)

// Fallback (no workspace): direct int32 consumption, 128^2 tile (round-2 proven).
__global__ void qgemm_fallback(const int* __restrict__ x32, const int* __restrict__ w32,
                               const int* __restrict__ bias, const float* __restrict__ wscale,
                               const float* __restrict__ iscale, const float* __restrict__ oscale,
                               const int* __restrict__ zp, int* __restrict__ out) {
    __shared__ int8_t As[128][64];
    __shared__ int8_t Bs[128][64];
    const int tid  = threadIdx.x;
    const int wave = tid >> 6;
    const int lane = tid & 63;
    int b = blockIdx.x;
    int s = (b & 7) * (gridDim.x >> 3) + (b >> 3);
    const int bcol = (s & 31) * 128;
    const int brow = (s >> 5) * 128;
    const int wr = wave >> 1;
    const int wc = wave & 1;
    i32x4 acc[4][4] = {};
    for (int kt = 0; kt < K_DIM; kt += 64) {
        int row = tid >> 1;
        int h = tid & 1;
        const i32x4* sa = (const i32x4*)(x32 + (size_t)(brow + row) * K_DIM + kt + h * 32);
        const i32x4* sb = (const i32x4*)(w32 + (size_t)(bcol + row) * K_DIM + kt + h * 32);
        int pa[8], pb[8];
        #pragma unroll
        for (int j = 0; j < 8; j++) { pa[j] = pack4(sa[j]); pb[j] = pack4(sb[j]); }
        *(i32x4*)&As[row][h * 32]      = *(i32x4*)&pa[0];
        *(i32x4*)&As[row][h * 32 + 16] = *(i32x4*)&pa[4];
        *(i32x4*)&Bs[row][h * 32]      = *(i32x4*)&pb[0];
        *(i32x4*)&Bs[row][h * 32 + 16] = *(i32x4*)&pb[4];
        __syncthreads();
        i32x4 a_frag[4], b_frag[4];
        #pragma unroll
        for (int m = 0; m < 4; m++)
            a_frag[m] = *(const i32x4*)&As[wr * 64 + m * 16 + (lane & 15)][(lane >> 4) * 16];
        #pragma unroll
        for (int n = 0; n < 4; n++)
            b_frag[n] = *(const i32x4*)&Bs[wc * 64 + n * 16 + (lane & 15)][(lane >> 4) * 16];
        #pragma unroll
        for (int m = 0; m < 4; m++)
            #pragma unroll
            for (int n = 0; n < 4; n++)
                acc[m][n] = MFMA_I8(a_frag[m], b_frag[n], acc[m][n]);
        __syncthreads();
    }
    const float is_v = iscale[0];
    const float os_v = oscale[0];
    const float zpf = (float)zp[0];
    #pragma unroll
    for (int n = 0; n < 4; n++) {
        int col = bcol + wc * 64 + n * 16 + (lane & 15);
        float sf = (is_v * wscale[col]) / os_v;
        int bz = bias[col];
        #pragma unroll
        for (int m = 0; m < 4; m++) {
            int row0 = brow + wr * 64 + m * 16 + (lane >> 4) * 4;
            #pragma unroll
            for (int r = 0; r < 4; r++) {
                float v = (float)(acc[m][n][r] + bz) * sf + zpf;
                v = rintf(v);
                v = fminf(fmaxf(v, -128.0f), 127.0f);
                out[(size_t)(row0 + r) * N_DIM + col] = (int)v;
            }
        }
    }
}

extern "C" void kernel_launch(void* const* d_in, const int* in_sizes, int n_in,
                              void* d_out, int out_size, void* d_ws, size_t ws_size,
                              hipStream_t stream) {
    const int*   x32    = (const int*)d_in[0];
    const int*   w32    = (const int*)d_in[1];
    const int*   bias   = (const int*)d_in[2];
    const float* wscale = (const float*)d_in[3];
    const float* iscale = (const float*)d_in[4];
    const float* oscale = (const float*)d_in[5];
    const int*   zp     = (const int*)d_in[6];
    int* out = (int*)d_out;

    const size_t need = (size_t)M_DIM * K_DIM + (size_t)N_DIM * K_DIM;  // 50.3 MB
    const size_t lds_bytes = 8 * (size_t)SLOT;                          // 131072

    if (ws_size >= need) {
        int8_t* xp = (int8_t*)d_ws;
        int8_t* wp = xp + (size_t)M_DIM * K_DIM;
        const int nblkA = (M_DIM / 32) * NKT2;   // 32768
        const int nblkB = (N_DIM / 32) * NKT2;   // 16384
        pack_panels32_kernel<<<nblkA / 4, 256, 0, stream>>>(x32, xp, nblkA);
        pack_panels32_kernel<<<nblkB / 4, 256, 0, stream>>>(w32, wp, nblkB);
        (void)hipFuncSetAttribute((const void*)qgemm32_kernel,
                                  hipFuncAttributeMaxDynamicSharedMemorySize,
                                  (int)lds_bytes);
        qgemm32_kernel<<<NBLK, 256, lds_bytes, stream>>>(xp, wp, bias, wscale, iscale, oscale, zp, out);
    } else {
        qgemm_fallback<<<2048, 256, 0, stream>>>(x32, w32, bias, wscale, iscale, oscale, zp, out);
    }
}